// Round 1
// baseline (704.794 us; speedup 1.0000x reference)
//
#include <hip/hip_runtime.h>
#include <hip/hip_bf16.h>

typedef __bf16 bf16x8 __attribute__((ext_vector_type(8)));
typedef __bf16 bf16x4 __attribute__((ext_vector_type(4)));
typedef float  f32x4  __attribute__((ext_vector_type(4)));

static constexpr int B = 2, S = 2048, D = 1024, H = 16, DK = 64;
static constexpr int M = B * S;          // 4096 rows
static constexpr int NE = M * D;         // 4194304 elements (one activation tensor)
static constexpr int WE = D * D;         // 1048576 elements (one weight matrix)

// ---------------- f32 -> bf16 conversion (vectorized, grid-stride) ----------
__global__ __launch_bounds__(256) void cvt_kernel(const float* __restrict__ src,
                                                  __bf16* __restrict__ dst, int n4) {
  int i = blockIdx.x * blockDim.x + threadIdx.x;
  int stride = gridDim.x * blockDim.x;
  for (; i < n4; i += stride) {
    float4 f = reinterpret_cast<const float4*>(src)[i];
    bf16x4 o;
    o[0] = (__bf16)f.x; o[1] = (__bf16)f.y; o[2] = (__bf16)f.z; o[3] = (__bf16)f.w;
    reinterpret_cast<bf16x4*>(dst)[i] = o;
  }
}

// ---------------- QKV projection: out = X @ W^T + b, epilogue RoPE / V^T ----
// one wave per 16x16 output tile; z = 0:Q (rope), 1:K (rope), 2:V (transpose)
__global__ __launch_bounds__(256) void proj_kernel(
    const __bf16* __restrict__ Xq, const __bf16* __restrict__ Xk,
    const __bf16* __restrict__ Xv, const __bf16* __restrict__ Wall,
    const float* __restrict__ bq, const float* __restrict__ bk,
    const float* __restrict__ bv,
    const float* __restrict__ sinp, const float* __restrict__ cosp,
    __bf16* __restrict__ Qr, __bf16* __restrict__ Kr, __bf16* __restrict__ Vt)
{
  int z = blockIdx.z;
  const __bf16* X; const __bf16* W; const float* bias;
  if (z == 0)      { X = Xq; W = Wall;          bias = bq; }
  else if (z == 1) { X = Xk; W = Wall + WE;     bias = bk; }
  else             { X = Xv; W = Wall + 2 * WE; bias = bv; }

  int lane = threadIdx.x & 63;
  int wid  = threadIdx.x >> 6;
  int tile = blockIdx.x;                 // 0..4095
  int mt = tile >> 4;                    // 0..255
  int nt = ((tile & 15) << 2) | wid;     // 0..63
  int m0 = mt * 16, n0 = nt * 16;
  int lr = lane & 15, lg = lane >> 4;
  int kg = lg * 8;

  const __bf16* Arow = X + (m0 + lr) * D;
  const __bf16* Brow = W + (n0 + lr) * D;
  f32x4 acc = {0.f, 0.f, 0.f, 0.f};
#pragma unroll 8
  for (int k0 = 0; k0 < D; k0 += 32) {
    bf16x8 a = *reinterpret_cast<const bf16x8*>(Arow + k0 + kg);
    bf16x8 b = *reinterpret_cast<const bf16x8*>(Brow + k0 + kg);
    acc = __builtin_amdgcn_mfma_f32_16x16x32_bf16(a, b, acc, 0, 0, 0);
  }

  int col = n0 + lr;
  int h = col >> 6, dk = col & 63, t = dk >> 1;
  float bval = bias[col];

  if (z < 2) {
    __bf16* dst = (z == 0) ? Qr : Kr;
#pragma unroll
    for (int i = 0; i < 4; ++i) {
      int r = m0 + lg * 4 + i;              // global row = b*S + s
      int s = r & (S - 1), bb = r >> 11;
      float val = acc[i] + bval;
      float part = __shfl_xor(val, 1);      // partner column (dk^1)
      float sn = sinp[s * 32 + t], cs = cosp[s * 32 + t];
      float out = (dk & 1) ? (part * sn + val * cs)    // odd:  x1*sin + x2*cos
                           : (val * cs - part * sn);   // even: x1*cos - x2*sin
      dst[((bb * H + h) * S + s) * DK + dk] = (__bf16)out;
    }
  } else {
#pragma unroll
    for (int i = 0; i < 4; ++i) {
      int r = m0 + lg * 4 + i;
      int s = r & (S - 1), bb = r >> 11;
      float val = acc[i] + bval;
      Vt[((bb * H + h) * DK + dk) * S + s] = (__bf16)val;   // V transposed
    }
  }
}

// ---------------- flash attention: 1 wave per 16 q-rows, KV blocks of 32 ----
__global__ __launch_bounds__(256) void attn_kernel(
    const __bf16* __restrict__ Qr, const __bf16* __restrict__ Kr,
    const __bf16* __restrict__ Vt, __bf16* __restrict__ AO)
{
  __shared__ __bf16 Plds[4][16][32];
  int lane = threadIdx.x & 63;
  int wid  = threadIdx.x >> 6;
  int gw = blockIdx.x * 4 + wid;
  int bh = gw >> 7;                 // 0..31  (b*H + h)
  int qt = gw & 127;
  int q0 = qt * 16;
  int lr = lane & 15, lg = lane >> 4, kg = lg * 8;

  const __bf16* Qh = Qr + bh * (S * DK);
  const __bf16* Kh = Kr + bh * (S * DK);
  const __bf16* Vh = Vt + bh * (DK * S);

  bf16x8 aq0 = *reinterpret_cast<const bf16x8*>(Qh + (q0 + lr) * DK + kg);
  bf16x8 aq1 = *reinterpret_cast<const bf16x8*>(Qh + (q0 + lr) * DK + 32 + kg);

  f32x4 o0 = {0,0,0,0}, o1 = {0,0,0,0}, o2 = {0,0,0,0}, o3 = {0,0,0,0};
  float mi[4], li[4];
#pragma unroll
  for (int i = 0; i < 4; ++i) { mi[i] = -1e30f; li[i] = 0.f; }

  int jmax = (q0 + 15) >> 5;
  for (int j = 0; j <= jmax; ++j) {
    int kv0 = j * 32;
    f32x4 sc0 = {0,0,0,0}, sc1 = {0,0,0,0};
    {
      const __bf16* Krow0 = Kh + (kv0 + lr) * DK;
      const __bf16* Krow1 = Kh + (kv0 + 16 + lr) * DK;
      sc0 = __builtin_amdgcn_mfma_f32_16x16x32_bf16(aq0, *reinterpret_cast<const bf16x8*>(Krow0 + kg),      sc0, 0,0,0);
      sc0 = __builtin_amdgcn_mfma_f32_16x16x32_bf16(aq1, *reinterpret_cast<const bf16x8*>(Krow0 + 32 + kg), sc0, 0,0,0);
      sc1 = __builtin_amdgcn_mfma_f32_16x16x32_bf16(aq0, *reinterpret_cast<const bf16x8*>(Krow1 + kg),      sc1, 0,0,0);
      sc1 = __builtin_amdgcn_mfma_f32_16x16x32_bf16(aq1, *reinterpret_cast<const bf16x8*>(Krow1 + 32 + kg), sc1, 0,0,0);
    }
    // scale + causal mask (score rows: r = q0 + lg*4 + i, cols: kv0 [+16] + lr)
#pragma unroll
    for (int i = 0; i < 4; ++i) {
      int r = q0 + lg * 4 + i;
      float s0 = sc0[i] * 0.125f; if (kv0 + lr > r)      s0 = -1e30f;
      float s1 = sc1[i] * 0.125f; if (kv0 + 16 + lr > r) s1 = -1e30f;
      sc0[i] = s0; sc1[i] = s1;
    }
    // online softmax (row lives in a 16-lane group -> shfl_xor reductions)
#pragma unroll
    for (int i = 0; i < 4; ++i) {
      float t = fmaxf(sc0[i], sc1[i]);
#pragma unroll
      for (int d2 = 1; d2 < 16; d2 <<= 1) t = fmaxf(t, __shfl_xor(t, d2));
      float mnew = fmaxf(mi[i], t);
      float f = __expf(mi[i] - mnew);
      mi[i] = mnew;
      li[i] *= f;
      o0[i] *= f; o1[i] *= f; o2[i] *= f; o3[i] *= f;
      float p0 = __expf(sc0[i] - mnew);
      float p1 = __expf(sc1[i] - mnew);
      float ps = p0 + p1;
#pragma unroll
      for (int d2 = 1; d2 < 16; d2 <<= 1) ps += __shfl_xor(ps, d2);
      li[i] += ps;
      Plds[wid][lg * 4 + i][lr]      = (__bf16)p0;
      Plds[wid][lg * 4 + i][16 + lr] = (__bf16)p1;
    }
    // PV: A = P (from LDS, re-layout), B = V^T rows (contiguous in s)
    bf16x8 ap = *reinterpret_cast<const bf16x8*>(&Plds[wid][lr][kg]);
    o0 = __builtin_amdgcn_mfma_f32_16x16x32_bf16(ap, *reinterpret_cast<const bf16x8*>(Vh + (0*16 + lr) * S + kv0 + kg), o0, 0,0,0);
    o1 = __builtin_amdgcn_mfma_f32_16x16x32_bf16(ap, *reinterpret_cast<const bf16x8*>(Vh + (1*16 + lr) * S + kv0 + kg), o1, 0,0,0);
    o2 = __builtin_amdgcn_mfma_f32_16x16x32_bf16(ap, *reinterpret_cast<const bf16x8*>(Vh + (2*16 + lr) * S + kv0 + kg), o2, 0,0,0);
    o3 = __builtin_amdgcn_mfma_f32_16x16x32_bf16(ap, *reinterpret_cast<const bf16x8*>(Vh + (3*16 + lr) * S + kv0 + kg), o3, 0,0,0);
  }

  // epilogue: AO[b, s, h, dk] (row-major (b*S+s) x 1024 for the final GEMM)
  int b = bh >> 4, h = bh & 15;
#pragma unroll
  for (int i = 0; i < 4; ++i) {
    int s = q0 + lg * 4 + i;
    float inv = 1.f / li[i];
    size_t base = ((size_t)(b * S + s) * H + h) * DK + lr;
    AO[base + 0]  = (__bf16)(o0[i] * inv);
    AO[base + 16] = (__bf16)(o1[i] * inv);
    AO[base + 32] = (__bf16)(o2[i] * inv);
    AO[base + 48] = (__bf16)(o3[i] * inv);
  }
}

// ---------------- output projection: out = AO @ Wo^T + bo (f32 out) --------
__global__ __launch_bounds__(256) void outproj_kernel(
    const __bf16* __restrict__ AO, const __bf16* __restrict__ Wo,
    const float* __restrict__ bo, float* __restrict__ out)
{
  int lane = threadIdx.x & 63;
  int wid  = threadIdx.x >> 6;
  int tile = blockIdx.x;
  int mt = tile >> 4;
  int nt = ((tile & 15) << 2) | wid;
  int m0 = mt * 16, n0 = nt * 16;
  int lr = lane & 15, lg = lane >> 4, kg = lg * 8;

  const __bf16* Arow = AO + (m0 + lr) * D;
  const __bf16* Brow = Wo + (n0 + lr) * D;
  f32x4 acc = {0.f, 0.f, 0.f, 0.f};
#pragma unroll 8
  for (int k0 = 0; k0 < D; k0 += 32) {
    bf16x8 a = *reinterpret_cast<const bf16x8*>(Arow + k0 + kg);
    bf16x8 b = *reinterpret_cast<const bf16x8*>(Brow + k0 + kg);
    acc = __builtin_amdgcn_mfma_f32_16x16x32_bf16(a, b, acc, 0, 0, 0);
  }
  int col = n0 + lr;
  float bval = bo[col];
#pragma unroll
  for (int i = 0; i < 4; ++i) {
    int r = m0 + lg * 4 + i;
    out[(size_t)r * D + col] = acc[i] + bval;
  }
}

extern "C" void kernel_launch(void* const* d_in, const int* in_sizes, int n_in,
                              void* d_out, int out_size, void* d_ws, size_t ws_size,
                              hipStream_t stream) {
  const float* k_in = (const float*)d_in[0];
  const float* q_in = (const float*)d_in[1];
  const float* v_in = (const float*)d_in[2];
  // d_in[3] = mask (tril) -> causal handled analytically
  const float* sinp = (const float*)d_in[4];
  const float* cosp = (const float*)d_in[5];
  const float* Wk = (const float*)d_in[6];
  const float* bk = (const float*)d_in[7];
  const float* Wq = (const float*)d_in[8];
  const float* bq = (const float*)d_in[9];
  const float* Wv = (const float*)d_in[10];
  const float* bv = (const float*)d_in[11];
  const float* Wo = (const float*)d_in[12];
  const float* bo = (const float*)d_in[13];
  float* out = (float*)d_out;

  __bf16* ws   = (__bf16*)d_ws;
  __bf16* Xq   = ws;                  // [4096][1024] bf16
  __bf16* Xk   = ws + NE;
  __bf16* Xv   = ws + 2 * NE;
  __bf16* Wall = ws + 3 * NE;         // Wq, Wk, Wv, Wo (each [1024][1024])
  __bf16* Qr   = ws + 3 * NE + 4 * WE; // (b,h,s,dk) rope'd
  __bf16* Kr   = Qr + NE;
  __bf16* Vt   = Kr + NE;             // (b,h,dk,s)
  __bf16* AO   = Vt + NE;             // (b,s,h,dk)

  dim3 blk(256);
  cvt_kernel<<<2048, blk, 0, stream>>>(q_in, Xq, NE / 4);
  cvt_kernel<<<2048, blk, 0, stream>>>(k_in, Xk, NE / 4);
  cvt_kernel<<<2048, blk, 0, stream>>>(v_in, Xv, NE / 4);
  cvt_kernel<<<1024, blk, 0, stream>>>(Wq, Wall,          WE / 4);
  cvt_kernel<<<1024, blk, 0, stream>>>(Wk, Wall + WE,     WE / 4);
  cvt_kernel<<<1024, blk, 0, stream>>>(Wv, Wall + 2 * WE, WE / 4);
  cvt_kernel<<<1024, blk, 0, stream>>>(Wo, Wall + 3 * WE, WE / 4);

  proj_kernel<<<dim3(4096, 1, 3), blk, 0, stream>>>(Xq, Xk, Xv, Wall, bq, bk, bv,
                                                    sinp, cosp, Qr, Kr, Vt);
  attn_kernel<<<1024, blk, 0, stream>>>(Qr, Kr, Vt, AO);
  outproj_kernel<<<4096, blk, 0, stream>>>(AO, Wall + 3 * WE, bo, out);
}

// Round 2
// 255.640 us; speedup vs baseline: 2.7570x; 2.7570x over previous
//
#include <hip/hip_runtime.h>
#include <hip/hip_bf16.h>

typedef __bf16 bf16x8 __attribute__((ext_vector_type(8)));
typedef __bf16 bf16x4 __attribute__((ext_vector_type(4)));
typedef float  f32x4  __attribute__((ext_vector_type(4)));

static constexpr int B = 2, S = 2048, D = 1024, H = 16, DK = 64;
static constexpr int M = B * S;          // 4096
static constexpr int NE = M * D;         // 4194304
static constexpr int WE = D * D;         // 1048576

__device__ inline void gload16(const void* g, void* l) {
  __builtin_amdgcn_global_load_lds(
      (const __attribute__((address_space(1))) void*)g,
      (__attribute__((address_space(3))) void*)l, 16, 0, 0);
}

// ---------------- f32 -> bf16 conversion, all tensors in one launch --------
__global__ __launch_bounds__(256) void cvt_all(
    const float* __restrict__ q, const float* __restrict__ k,
    const float* __restrict__ v, const float* __restrict__ Wq,
    const float* __restrict__ Wk, const float* __restrict__ Wv,
    const float* __restrict__ Wo,
    __bf16* __restrict__ Xq, __bf16* __restrict__ Xk,
    __bf16* __restrict__ Xv, __bf16* __restrict__ Wall)
{
  int z = blockIdx.y;
  const float* src; __bf16* dst; int n4;
  switch (z) {
    case 0: src = q;  dst = Xq;            n4 = NE / 4; break;
    case 1: src = k;  dst = Xk;            n4 = NE / 4; break;
    case 2: src = v;  dst = Xv;            n4 = NE / 4; break;
    case 3: src = Wq; dst = Wall;          n4 = WE / 4; break;
    case 4: src = Wk; dst = Wall + WE;     n4 = WE / 4; break;
    case 5: src = Wv; dst = Wall + 2*WE;   n4 = WE / 4; break;
    default:src = Wo; dst = Wall + 3*WE;   n4 = WE / 4; break;
  }
  int i = blockIdx.x * blockDim.x + threadIdx.x;
  int stride = gridDim.x * blockDim.x;
  for (; i < n4; i += stride) {
    float4 f = reinterpret_cast<const float4*>(src)[i];
    bf16x4 o;
    o[0] = (__bf16)f.x; o[1] = (__bf16)f.y; o[2] = (__bf16)f.z; o[3] = (__bf16)f.w;
    reinterpret_cast<bf16x4*>(dst)[i] = o;
  }
}

// ---------------- fused QKV projection, m97-structure 128x128 GEMM ---------
// C[M=4096, Nfused=3072] = X_z @ W_z^T + b_z ; epilogue RoPE (Q,K) / V^T
__global__ __launch_bounds__(256) void proj_kernel(
    const __bf16* __restrict__ Xq, const __bf16* __restrict__ Xk,
    const __bf16* __restrict__ Xv, const __bf16* __restrict__ Wall,
    const float* __restrict__ bq_, const float* __restrict__ bk_,
    const float* __restrict__ bv_,
    const float* __restrict__ sinp, const float* __restrict__ cosp,
    __bf16* __restrict__ Qr, __bf16* __restrict__ Kr, __bf16* __restrict__ Vt)
{
  __shared__ __align__(16) __bf16 As[128 * 32];
  __shared__ __align__(16) __bf16 Bs[128 * 32];
  int tid = threadIdx.x;
  int lane = tid & 63, wid = tid >> 6;
  int lr = lane & 15, lg = lane >> 4;
  int wr = wid >> 1, wc = wid & 1;
  int m0 = blockIdx.x * 128;
  int by = blockIdx.y;                  // 0..23 (fused n-tile)
  int z  = by >> 3;                     // 0:Q 1:K 2:V (block-uniform)
  const __bf16* A    = (z == 0) ? Xq : (z == 1) ? Xk : Xv;
  const __bf16* Bw   = Wall + (size_t)by * 128 * 1024;
  const float*  bias = (z == 0) ? bq_ : (z == 1) ? bk_ : bv_;

  int off0 = tid * 16;                  // byte offset in 8KB tile (iter 0)
  int row0 = off0 >> 6;                 // 64 B per LDS row (32 bf16)
  int ce0  = (off0 & 63) >> 1;          // element col within row
  char* asw = (char*)As + wid * 1024;   // wave-uniform LDS dest base
  char* bsw = (char*)Bs + wid * 1024;

  f32x4 acc[4][4];
#pragma unroll
  for (int i = 0; i < 4; ++i)
#pragma unroll
    for (int j = 0; j < 4; ++j) acc[i][j] = (f32x4){0, 0, 0, 0};

  for (int k0 = 0; k0 < 1024; k0 += 32) {
    gload16(A  + (size_t)(m0 + row0)      * 1024 + k0 + ce0, asw);
    gload16(A  + (size_t)(m0 + row0 + 64) * 1024 + k0 + ce0, asw + 4096);
    gload16(Bw + (size_t)(row0)           * 1024 + k0 + ce0, bsw);
    gload16(Bw + (size_t)(row0 + 64)      * 1024 + k0 + ce0, bsw + 4096);
    __syncthreads();
    bf16x8 af[4], bf[4];
#pragma unroll
    for (int mi = 0; mi < 4; ++mi)
      af[mi] = *reinterpret_cast<const bf16x8*>(&As[(wr*64 + mi*16 + lr)*32 + lg*8]);
#pragma unroll
    for (int ni = 0; ni < 4; ++ni)
      bf[ni] = *reinterpret_cast<const bf16x8*>(&Bs[(wc*64 + ni*16 + lr)*32 + lg*8]);
#pragma unroll
    for (int mi = 0; mi < 4; ++mi)
#pragma unroll
      for (int ni = 0; ni < 4; ++ni)
        acc[mi][ni] = __builtin_amdgcn_mfma_f32_16x16x32_bf16(af[mi], bf[ni], acc[mi][ni], 0, 0, 0);
    __syncthreads();
  }

  // epilogue
#pragma unroll
  for (int ni = 0; ni < 4; ++ni) {
    int cf  = by * 128 + wc * 64 + ni * 16 + lr;   // fused col
    int col = cf & 1023;
    int h = col >> 6, dk = col & 63, tt = dk >> 1;
    float bval = bias[col];
#pragma unroll
    for (int mi = 0; mi < 4; ++mi) {
#pragma unroll
      for (int i = 0; i < 4; ++i) {
        int r = m0 + wr * 64 + mi * 16 + lg * 4 + i;
        int s = r & (S - 1), bb = r >> 11;
        float val = acc[mi][ni][i] + bval;
        if (z < 2) {
          float part = __shfl_xor(val, 1);
          float sn = sinp[s * 32 + tt], cs = cosp[s * 32 + tt];
          float ov = (dk & 1) ? (part * sn + val * cs) : (val * cs - part * sn);
          __bf16* dst = (z == 0) ? Qr : Kr;
          dst[((size_t)(bb * H + h) * S + s) * DK + dk] = (__bf16)ov;
        } else {
          Vt[((size_t)(bb * H + h) * DK + dk) * S + s] = (__bf16)val;
        }
      }
    }
  }
}

// ---------------- output projection, same GEMM structure, f32 out ----------
__global__ __launch_bounds__(256) void outproj_kernel(
    const __bf16* __restrict__ AO, const __bf16* __restrict__ Wo,
    const float* __restrict__ bo_, float* __restrict__ out)
{
  __shared__ __align__(16) __bf16 As[128 * 32];
  __shared__ __align__(16) __bf16 Bs[128 * 32];
  int tid = threadIdx.x;
  int lane = tid & 63, wid = tid >> 6;
  int lr = lane & 15, lg = lane >> 4;
  int wr = wid >> 1, wc = wid & 1;
  int m0 = blockIdx.x * 128;
  int n0 = blockIdx.y * 128;

  int off0 = tid * 16;
  int row0 = off0 >> 6;
  int ce0  = (off0 & 63) >> 1;
  char* asw = (char*)As + wid * 1024;
  char* bsw = (char*)Bs + wid * 1024;

  f32x4 acc[4][4];
#pragma unroll
  for (int i = 0; i < 4; ++i)
#pragma unroll
    for (int j = 0; j < 4; ++j) acc[i][j] = (f32x4){0, 0, 0, 0};

  for (int k0 = 0; k0 < 1024; k0 += 32) {
    gload16(AO + (size_t)(m0 + row0)      * 1024 + k0 + ce0, asw);
    gload16(AO + (size_t)(m0 + row0 + 64) * 1024 + k0 + ce0, asw + 4096);
    gload16(Wo + (size_t)(n0 + row0)      * 1024 + k0 + ce0, bsw);
    gload16(Wo + (size_t)(n0 + row0 + 64) * 1024 + k0 + ce0, bsw + 4096);
    __syncthreads();
    bf16x8 af[4], bf[4];
#pragma unroll
    for (int mi = 0; mi < 4; ++mi)
      af[mi] = *reinterpret_cast<const bf16x8*>(&As[(wr*64 + mi*16 + lr)*32 + lg*8]);
#pragma unroll
    for (int ni = 0; ni < 4; ++ni)
      bf[ni] = *reinterpret_cast<const bf16x8*>(&Bs[(wc*64 + ni*16 + lr)*32 + lg*8]);
#pragma unroll
    for (int mi = 0; mi < 4; ++mi)
#pragma unroll
      for (int ni = 0; ni < 4; ++ni)
        acc[mi][ni] = __builtin_amdgcn_mfma_f32_16x16x32_bf16(af[mi], bf[ni], acc[mi][ni], 0, 0, 0);
    __syncthreads();
  }

#pragma unroll
  for (int ni = 0; ni < 4; ++ni) {
    int c = n0 + wc * 64 + ni * 16 + lr;
    float bval = bo_[c];
#pragma unroll
    for (int mi = 0; mi < 4; ++mi)
#pragma unroll
      for (int i = 0; i < 4; ++i) {
        int r = m0 + wr * 64 + mi * 16 + lg * 4 + i;
        out[(size_t)r * 1024 + c] = acc[mi][ni][i] + bval;
      }
  }
}

// ---------------- flash attention: 1 wave per 32 q-rows, KV blocks of 64 ---
__global__ __launch_bounds__(256) void attn_kernel(
    const __bf16* __restrict__ Qr, const __bf16* __restrict__ Kr,
    const __bf16* __restrict__ Vt, __bf16* __restrict__ AO)
{
  __shared__ __align__(16) __bf16 Plds[4][32 * 64];   // per-wave 4KB P tile
  int lane = threadIdx.x & 63, wid = threadIdx.x >> 6;
  int lr = lane & 15, lg = lane >> 4, kg = lg * 8;
  int gw = blockIdx.x * 4 + wid;
  int bh = gw >> 6;                 // 64 q-tiles per (b,h)
  int qt = gw & 63;
  int q0 = qt * 32;
  const __bf16* Qh = Qr + (size_t)bh * (S * DK);
  const __bf16* Kh = Kr + (size_t)bh * (S * DK);
  const __bf16* Vh = Vt + (size_t)bh * (DK * S);
  char* P = (char*)&Plds[wid][0];

  bf16x8 aq[2][2];
#pragma unroll
  for (int mi = 0; mi < 2; ++mi)
#pragma unroll
    for (int kc = 0; kc < 2; ++kc)
      aq[mi][kc] = *reinterpret_cast<const bf16x8*>(Qh + (q0 + mi*16 + lr)*DK + kc*32 + kg);

  f32x4 o[2][4];
  float mrow[2][4], lrow[2][4];
#pragma unroll
  for (int mi = 0; mi < 2; ++mi) {
#pragma unroll
    for (int d = 0; d < 4; ++d) o[mi][d] = (f32x4){0, 0, 0, 0};
#pragma unroll
    for (int i = 0; i < 4; ++i) { mrow[mi][i] = -1e30f; lrow[mi][i] = 0.f; }
  }

  int jmax = (q0 + 31) >> 6;
  for (int j = 0; j <= jmax; ++j) {
    int kv0 = j * 64;
    f32x4 sc[2][4];
#pragma unroll
    for (int mi = 0; mi < 2; ++mi)
#pragma unroll
      for (int nj = 0; nj < 4; ++nj) sc[mi][nj] = (f32x4){0, 0, 0, 0};
#pragma unroll
    for (int nj = 0; nj < 4; ++nj) {
#pragma unroll
      for (int kc = 0; kc < 2; ++kc) {
        bf16x8 kf = *reinterpret_cast<const bf16x8*>(Kh + (kv0 + nj*16 + lr)*DK + kc*32 + kg);
#pragma unroll
        for (int mi = 0; mi < 2; ++mi)
          sc[mi][nj] = __builtin_amdgcn_mfma_f32_16x16x32_bf16(aq[mi][kc], kf, sc[mi][nj], 0, 0, 0);
      }
    }
    // scale + causal mask
#pragma unroll
    for (int mi = 0; mi < 2; ++mi)
#pragma unroll
      for (int nj = 0; nj < 4; ++nj)
#pragma unroll
        for (int i = 0; i < 4; ++i) {
          int r = q0 + mi*16 + lg*4 + i;
          int c = kv0 + nj*16 + lr;
          float v = sc[mi][nj][i] * 0.125f;
          sc[mi][nj][i] = (c > r) ? -1e30f : v;
        }
    // online softmax (rows live in 16-lane groups)
#pragma unroll
    for (int mi = 0; mi < 2; ++mi)
#pragma unroll
      for (int i = 0; i < 4; ++i) {
        float t = fmaxf(fmaxf(sc[mi][0][i], sc[mi][1][i]),
                        fmaxf(sc[mi][2][i], sc[mi][3][i]));
#pragma unroll
        for (int d2 = 1; d2 < 16; d2 <<= 1) t = fmaxf(t, __shfl_xor(t, d2));
        float mnew = fmaxf(mrow[mi][i], t);
        float f = __expf(mrow[mi][i] - mnew);
        mrow[mi][i] = mnew;
        lrow[mi][i] *= f;
#pragma unroll
        for (int d = 0; d < 4; ++d) o[mi][d][i] *= f;
        float p[4], ps = 0.f;
#pragma unroll
        for (int nj = 0; nj < 4; ++nj) { p[nj] = __expf(sc[mi][nj][i] - mnew); ps += p[nj]; }
#pragma unroll
        for (int d2 = 1; d2 < 16; d2 <<= 1) ps += __shfl_xor(ps, d2);
        lrow[mi][i] += ps;
        int row = mi*16 + lg*4 + i;
        int swz = (row & 7) << 4;
#pragma unroll
        for (int nj = 0; nj < 4; ++nj) {
          int bofs = row * 128 + (nj*16 + lr) * 2;
          *(__bf16*)(P + (bofs ^ swz)) = (__bf16)p[nj];
        }
      }
    // PV
    bf16x8 ap[2][2];
#pragma unroll
    for (int mi = 0; mi < 2; ++mi)
#pragma unroll
      for (int kc = 0; kc < 2; ++kc) {
        int row = mi*16 + lr;
        int bofs = row * 128 + kc*64 + lg*16;
        ap[mi][kc] = *(const bf16x8*)(P + (bofs ^ ((row & 7) << 4)));
      }
#pragma unroll
    for (int d = 0; d < 4; ++d) {
#pragma unroll
      for (int kc = 0; kc < 2; ++kc) {
        bf16x8 vf = *reinterpret_cast<const bf16x8*>(Vh + (size_t)(d*16 + lr)*S + kv0 + kc*32 + kg);
#pragma unroll
        for (int mi = 0; mi < 2; ++mi)
          o[mi][d] = __builtin_amdgcn_mfma_f32_16x16x32_bf16(ap[mi][kc], vf, o[mi][d], 0, 0, 0);
      }
    }
  }

  // epilogue: AO[b, s, h, dk]
  int b = bh >> 4, h = bh & 15;
#pragma unroll
  for (int mi = 0; mi < 2; ++mi)
#pragma unroll
    for (int i = 0; i < 4; ++i) {
      int s = q0 + mi*16 + lg*4 + i;
      float inv = 1.f / lrow[mi][i];
      size_t base = ((size_t)(b * S + s) * H + h) * DK + lr;
#pragma unroll
      for (int d = 0; d < 4; ++d)
        AO[base + d*16] = (__bf16)(o[mi][d][i] * inv);
    }
}

extern "C" void kernel_launch(void* const* d_in, const int* in_sizes, int n_in,
                              void* d_out, int out_size, void* d_ws, size_t ws_size,
                              hipStream_t stream) {
  const float* k_in = (const float*)d_in[0];
  const float* q_in = (const float*)d_in[1];
  const float* v_in = (const float*)d_in[2];
  const float* sinp = (const float*)d_in[4];
  const float* cosp = (const float*)d_in[5];
  const float* Wk = (const float*)d_in[6];
  const float* bk = (const float*)d_in[7];
  const float* Wq = (const float*)d_in[8];
  const float* bq = (const float*)d_in[9];
  const float* Wv = (const float*)d_in[10];
  const float* bv = (const float*)d_in[11];
  const float* Wo = (const float*)d_in[12];
  const float* bo = (const float*)d_in[13];
  float* out = (float*)d_out;

  __bf16* ws   = (__bf16*)d_ws;
  __bf16* Xq   = ws;                   // [4096][1024]
  __bf16* Xk   = ws + NE;
  __bf16* Xv   = ws + 2 * NE;
  __bf16* Wall = ws + 3 * NE;          // [Wq|Wk|Wv|Wo]
  __bf16* Qr   = ws + 3 * NE + 4 * WE; // (b,h,s,dk)
  __bf16* Kr   = Qr + NE;
  __bf16* Vt   = Kr + NE;              // (b,h,dk,s)
  __bf16* AO   = Vt + NE;              // (b,s,h,dk)

  dim3 blk(256);
  cvt_all<<<dim3(512, 7), blk, 0, stream>>>(q_in, k_in, v_in, Wq, Wk, Wv, Wo,
                                            Xq, Xk, Xv, Wall);
  proj_kernel<<<dim3(32, 24), blk, 0, stream>>>(Xq, Xk, Xv, Wall, bq, bk, bv,
                                                sinp, cosp, Qr, Kr, Vt);
  attn_kernel<<<512, blk, 0, stream>>>(Qr, Kr, Vt, AO);
  outproj_kernel<<<dim3(32, 8), blk, 0, stream>>>(AO, Wall + 3 * WE, bo, out);
}

// Round 4
// 225.505 us; speedup vs baseline: 3.1254x; 1.1336x over previous
//
#include <hip/hip_runtime.h>
#include <hip/hip_bf16.h>

typedef __bf16 bf16x8 __attribute__((ext_vector_type(8)));
typedef __bf16 bf16x4 __attribute__((ext_vector_type(4)));
typedef float  f32x4  __attribute__((ext_vector_type(4)));

static constexpr int B = 2, S = 2048, D = 1024, H = 16, DK = 64;
static constexpr int M = B * S;          // 4096
static constexpr int NE = M * D;         // 4194304
static constexpr int WE = D * D;         // 1048576

__device__ inline float fast_exp2(float x) { return __builtin_amdgcn_exp2f(x); }

__device__ inline void gload16(const void* g, void* l) {
  __builtin_amdgcn_global_load_lds(
      (const __attribute__((address_space(1))) void*)g,
      (__attribute__((address_space(3))) void*)l, 16, 0, 0);
}

// ---------------- f32 -> bf16 conversion, all tensors in one launch --------
__global__ __launch_bounds__(256) void cvt_all(
    const float* __restrict__ q, const float* __restrict__ k,
    const float* __restrict__ v, const float* __restrict__ Wq,
    const float* __restrict__ Wk, const float* __restrict__ Wv,
    const float* __restrict__ Wo,
    __bf16* __restrict__ Xq, __bf16* __restrict__ Xk,
    __bf16* __restrict__ Xv, __bf16* __restrict__ Wall)
{
  int z = blockIdx.y;
  const float* src; __bf16* dst; int n4;
  switch (z) {
    case 0: src = q;  dst = Xq;            n4 = NE / 4; break;
    case 1: src = k;  dst = Xk;            n4 = NE / 4; break;
    case 2: src = v;  dst = Xv;            n4 = NE / 4; break;
    case 3: src = Wq; dst = Wall;          n4 = WE / 4; break;
    case 4: src = Wk; dst = Wall + WE;     n4 = WE / 4; break;
    case 5: src = Wv; dst = Wall + 2*WE;   n4 = WE / 4; break;
    default:src = Wo; dst = Wall + 3*WE;   n4 = WE / 4; break;
  }
  int i = blockIdx.x * blockDim.x + threadIdx.x;
  int stride = gridDim.x * blockDim.x;
  for (; i < n4; i += stride) {
    float4 f = reinterpret_cast<const float4*>(src)[i];
    bf16x4 o;
    o[0] = (__bf16)f.x; o[1] = (__bf16)f.y; o[2] = (__bf16)f.z; o[3] = (__bf16)f.w;
    reinterpret_cast<bf16x4*>(dst)[i] = o;
  }
}

// ---------------- fused QKV projection, m97-structure 128x128 GEMM ---------
// C[M=4096, Nfused=3072] = X_z @ W_z^T + b_z ; epilogue RoPE (Q,K) / V^T
// Q additionally pre-scaled by 0.125*log2(e) so attention works in exp2 space.
__global__ __launch_bounds__(256) void proj_kernel(
    const __bf16* __restrict__ Xq, const __bf16* __restrict__ Xk,
    const __bf16* __restrict__ Xv, const __bf16* __restrict__ Wall,
    const float* __restrict__ bq_, const float* __restrict__ bk_,
    const float* __restrict__ bv_,
    const float* __restrict__ sinp, const float* __restrict__ cosp,
    __bf16* __restrict__ Qr, __bf16* __restrict__ Kr, __bf16* __restrict__ Vt)
{
  __shared__ __align__(16) __bf16 As[128 * 32];
  __shared__ __align__(16) __bf16 Bs[128 * 32];
  int tid = threadIdx.x;
  int lane = tid & 63, wid = tid >> 6;
  int lr = lane & 15, lg = lane >> 4;
  int wr = wid >> 1, wc = wid & 1;
  int m0 = blockIdx.x * 128;
  int by = blockIdx.y;                  // 0..23 (fused n-tile)
  int z  = by >> 3;                     // 0:Q 1:K 2:V (block-uniform)
  const __bf16* A    = (z == 0) ? Xq : (z == 1) ? Xk : Xv;
  const __bf16* Bw   = Wall + (size_t)by * 128 * 1024;
  const float*  bias = (z == 0) ? bq_ : (z == 1) ? bk_ : bv_;

  int off0 = tid * 16;                  // byte offset in 8KB tile
  int row0 = off0 >> 6;                 // 64 B per LDS row (32 bf16)
  int ce0  = (off0 & 63) >> 1;
  char* asw = (char*)As + wid * 1024;
  char* bsw = (char*)Bs + wid * 1024;

  f32x4 acc[4][4];
#pragma unroll
  for (int i = 0; i < 4; ++i)
#pragma unroll
    for (int j = 0; j < 4; ++j) acc[i][j] = (f32x4){0, 0, 0, 0};

  for (int k0 = 0; k0 < 1024; k0 += 32) {
    gload16(A  + (size_t)(m0 + row0)      * 1024 + k0 + ce0, asw);
    gload16(A  + (size_t)(m0 + row0 + 64) * 1024 + k0 + ce0, asw + 4096);
    gload16(Bw + (size_t)(row0)           * 1024 + k0 + ce0, bsw);
    gload16(Bw + (size_t)(row0 + 64)      * 1024 + k0 + ce0, bsw + 4096);
    __syncthreads();
    bf16x8 af[4], bf[4];
#pragma unroll
    for (int mi = 0; mi < 4; ++mi)
      af[mi] = *reinterpret_cast<const bf16x8*>(&As[(wr*64 + mi*16 + lr)*32 + lg*8]);
#pragma unroll
    for (int ni = 0; ni < 4; ++ni)
      bf[ni] = *reinterpret_cast<const bf16x8*>(&Bs[(wc*64 + ni*16 + lr)*32 + lg*8]);
#pragma unroll
    for (int mi = 0; mi < 4; ++mi)
#pragma unroll
      for (int ni = 0; ni < 4; ++ni)
        acc[mi][ni] = __builtin_amdgcn_mfma_f32_16x16x32_bf16(af[mi], bf[ni], acc[mi][ni], 0, 0, 0);
    __syncthreads();
  }

#pragma unroll
  for (int ni = 0; ni < 4; ++ni) {
    int cf  = by * 128 + wc * 64 + ni * 16 + lr;
    int col = cf & 1023;
    int h = col >> 6, dk = col & 63, tt = dk >> 1;
    float bval = bias[col];
#pragma unroll
    for (int mi = 0; mi < 4; ++mi) {
#pragma unroll
      for (int i = 0; i < 4; ++i) {
        int r = m0 + wr * 64 + mi * 16 + lg * 4 + i;
        int s = r & (S - 1), bb = r >> 11;
        float val = acc[mi][ni][i] + bval;
        if (z < 2) {
          float part = __shfl_xor(val, 1);
          float sn = sinp[s * 32 + tt], cs = cosp[s * 32 + tt];
          float ov = (dk & 1) ? (part * sn + val * cs) : (val * cs - part * sn);
          if (z == 0) ov *= 0.18033688011112042f;   // 0.125 * log2(e)
          __bf16* dst = (z == 0) ? Qr : Kr;
          dst[((size_t)(bb * H + h) * S + s) * DK + dk] = (__bf16)ov;
        } else {
          Vt[((size_t)(bb * H + h) * DK + dk) * S + s] = (__bf16)val;
        }
      }
    }
  }
}

// ---------------- output projection, same GEMM structure, f32 out ----------
__global__ __launch_bounds__(256) void outproj_kernel(
    const __bf16* __restrict__ AO, const __bf16* __restrict__ Wo,
    const float* __restrict__ bo_, float* __restrict__ out)
{
  __shared__ __align__(16) __bf16 As[128 * 32];
  __shared__ __align__(16) __bf16 Bs[128 * 32];
  int tid = threadIdx.x;
  int lane = tid & 63, wid = tid >> 6;
  int lr = lane & 15, lg = lane >> 4;
  int wr = wid >> 1, wc = wid & 1;
  int m0 = blockIdx.x * 128;
  int n0 = blockIdx.y * 128;

  int off0 = tid * 16;
  int row0 = off0 >> 6;
  int ce0  = (off0 & 63) >> 1;
  char* asw = (char*)As + wid * 1024;
  char* bsw = (char*)Bs + wid * 1024;

  f32x4 acc[4][4];
#pragma unroll
  for (int i = 0; i < 4; ++i)
#pragma unroll
    for (int j = 0; j < 4; ++j) acc[i][j] = (f32x4){0, 0, 0, 0};

  for (int k0 = 0; k0 < 1024; k0 += 32) {
    gload16(AO + (size_t)(m0 + row0)      * 1024 + k0 + ce0, asw);
    gload16(AO + (size_t)(m0 + row0 + 64) * 1024 + k0 + ce0, asw + 4096);
    gload16(Wo + (size_t)(n0 + row0)      * 1024 + k0 + ce0, bsw);
    gload16(Wo + (size_t)(n0 + row0 + 64) * 1024 + k0 + ce0, bsw + 4096);
    __syncthreads();
    bf16x8 af[4], bf[4];
#pragma unroll
    for (int mi = 0; mi < 4; ++mi)
      af[mi] = *reinterpret_cast<const bf16x8*>(&As[(wr*64 + mi*16 + lr)*32 + lg*8]);
#pragma unroll
    for (int ni = 0; ni < 4; ++ni)
      bf[ni] = *reinterpret_cast<const bf16x8*>(&Bs[(wc*64 + ni*16 + lr)*32 + lg*8]);
#pragma unroll
    for (int mi = 0; mi < 4; ++mi)
#pragma unroll
      for (int ni = 0; ni < 4; ++ni)
        acc[mi][ni] = __builtin_amdgcn_mfma_f32_16x16x32_bf16(af[mi], bf[ni], acc[mi][ni], 0, 0, 0);
    __syncthreads();
  }

#pragma unroll
  for (int ni = 0; ni < 4; ++ni) {
    int c = n0 + wc * 64 + ni * 16 + lr;
    float bval = bo_[c];
#pragma unroll
    for (int mi = 0; mi < 4; ++mi)
#pragma unroll
      for (int i = 0; i < 4; ++i) {
        int r = m0 + wr * 64 + mi * 16 + lg * 4 + i;
        out[(size_t)r * 1024 + c] = acc[mi][ni][i] + bval;
      }
  }
}

// ---------------- flash attention: swapped-operand, softmax fully in-reg ---
// One wave per 32 q-rows. QK^T = mfma(K,Q) -> lane holds score row q=lane&15.
// PV = mfma(V^T,P) with identical k-permutation on both operands (zero-shuffle).
template<bool MASKED, bool LOADNEXT>
__device__ __forceinline__ void attn_step(
    const __bf16* __restrict__ Kh, const __bf16* __restrict__ Vh,
    int kv0, int q0, int lr, int lg,
    const bf16x8 (&bq)[2][2], bf16x8 (&kaC)[4][2], bf16x8 (&kaN)[4][2],
    f32x4 (&o)[2][4], float (&m2)[2], float (&l2)[2])
{
  // V loads issued early (latency hides under QK^T + softmax)
  bf16x8 va[4][2];
#pragma unroll
  for (int dt = 0; dt < 4; ++dt)
#pragma unroll
    for (int kc = 0; kc < 2; ++kc) {
      const __bf16* vb = Vh + (size_t)(dt * 16 + lr) * S + kv0 + kc * 32 + lg * 4;
      union { bf16x8 v8; bf16x4 v4[2]; } u;
      u.v4[0] = *(const bf16x4*)vb;
      u.v4[1] = *(const bf16x4*)(vb + 16);
      va[dt][kc] = u.v8;
    }

  f32x4 sc[2][4];
#pragma unroll
  for (int qt2 = 0; qt2 < 2; ++qt2)
#pragma unroll
    for (int kt = 0; kt < 4; ++kt) sc[qt2][kt] = (f32x4){0, 0, 0, 0};
#pragma unroll
  for (int kt = 0; kt < 4; ++kt)
#pragma unroll
    for (int kc = 0; kc < 2; ++kc)
#pragma unroll
      for (int qt2 = 0; qt2 < 2; ++qt2)
        sc[qt2][kt] = __builtin_amdgcn_mfma_f32_16x16x32_bf16(
            kaC[kt][kc], bq[qt2][kc], sc[qt2][kt], 0, 0, 0);

  if (LOADNEXT) {
#pragma unroll
    for (int kt = 0; kt < 4; ++kt)
#pragma unroll
      for (int kc = 0; kc < 2; ++kc)
        kaN[kt][kc] = *(const bf16x8*)(Kh + (size_t)(kv0 + 64 + kt * 16 + lr) * DK + kc * 32 + lg * 8);
  }

  if (MASKED) {
#pragma unroll
    for (int qt2 = 0; qt2 < 2; ++qt2)
#pragma unroll
      for (int kt = 0; kt < 4; ++kt)
#pragma unroll
        for (int i = 0; i < 4; ++i)
          if (kv0 + kt * 16 + lg * 4 + i > q0 + qt2 * 16 + lr)
            sc[qt2][kt][i] = -3e38f;
  }

  bf16x8 pb[2][2];
#pragma unroll
  for (int qt2 = 0; qt2 < 2; ++qt2) {
    // row max: 16 in-lane values + 2 cross-group shfl
    float tm = fmaxf(
        fmaxf(fmaxf(fmaxf(sc[qt2][0][0], sc[qt2][0][1]), fmaxf(sc[qt2][0][2], sc[qt2][0][3])),
              fmaxf(fmaxf(sc[qt2][1][0], sc[qt2][1][1]), fmaxf(sc[qt2][1][2], sc[qt2][1][3]))),
        fmaxf(fmaxf(fmaxf(sc[qt2][2][0], sc[qt2][2][1]), fmaxf(sc[qt2][2][2], sc[qt2][2][3])),
              fmaxf(fmaxf(sc[qt2][3][0], sc[qt2][3][1]), fmaxf(sc[qt2][3][2], sc[qt2][3][3]))));
    tm = fmaxf(tm, __shfl_xor(tm, 16));
    tm = fmaxf(tm, __shfl_xor(tm, 32));
    // defer-max (T13, THR=8 in log2 space)
    if (__any(tm > m2[qt2] + 8.0f)) {
      float mn = fmaxf(m2[qt2], tm);
      float f = fast_exp2(m2[qt2] - mn);
      m2[qt2] = mn;
      l2[qt2] *= f;
#pragma unroll
      for (int dt = 0; dt < 4; ++dt) o[qt2][dt] *= f;
    }
    float m = m2[qt2];
    float p[16];
#pragma unroll
    for (int kt = 0; kt < 4; ++kt)
#pragma unroll
      for (int i = 0; i < 4; ++i)
        p[kt * 4 + i] = fast_exp2(sc[qt2][kt][i] - m);
    float s01 = (p[0] + p[1]) + (p[2] + p[3]);
    float s23 = (p[4] + p[5]) + (p[6] + p[7]);
    float s45 = (p[8] + p[9]) + (p[10] + p[11]);
    float s67 = (p[12] + p[13]) + (p[14] + p[15]);
    float sum = (s01 + s23) + (s45 + s67);
    sum += __shfl_xor(sum, 16);
    sum += __shfl_xor(sum, 32);
    l2[qt2] += sum;
    // P fragments, zero-shuffle: elem j=4a+r  <->  k = kv0+32kc+16a+4lg+r
#pragma unroll
    for (int kc = 0; kc < 2; ++kc) {
      bf16x8 pv;
#pragma unroll
      for (int a = 0; a < 2; ++a)
#pragma unroll
        for (int r = 0; r < 4; ++r)
          pv[a * 4 + r] = (__bf16)p[(2 * kc + a) * 4 + r];
      pb[qt2][kc] = pv;
    }
  }

  // PV: o[qt2][dt] lane holds q=lane&15 (col), d = 16*dt + 4*lg + reg (row)
#pragma unroll
  for (int dt = 0; dt < 4; ++dt)
#pragma unroll
    for (int kc = 0; kc < 2; ++kc)
#pragma unroll
      for (int qt2 = 0; qt2 < 2; ++qt2)
        o[qt2][dt] = __builtin_amdgcn_mfma_f32_16x16x32_bf16(
            va[dt][kc], pb[qt2][kc], o[qt2][dt], 0, 0, 0);
}

__global__ __launch_bounds__(64, 2) void attn_kernel(
    const __bf16* __restrict__ Qr, const __bf16* __restrict__ Kr,
    const __bf16* __restrict__ Vt, __bf16* __restrict__ AO)
{
  int lane = threadIdx.x;
  int lr = lane & 15, lg = lane >> 4;
  int bx = blockIdx.x;
  // heavy-first, XCD-clustered mapping: bh per XCD chunk, qt descending
  int bh = (bx & 7) * 4 + ((bx >> 3) & 3);
  int qt = 63 - (bx >> 5);
  int q0 = qt * 32;
  const __bf16* Qh = Qr + (size_t)bh * (S * DK);
  const __bf16* Kh = Kr + (size_t)bh * (S * DK);
  const __bf16* Vh = Vt + (size_t)bh * (DK * S);

  bf16x8 bq[2][2];
#pragma unroll
  for (int qt2 = 0; qt2 < 2; ++qt2)
#pragma unroll
    for (int kc = 0; kc < 2; ++kc)
      bq[qt2][kc] = *(const bf16x8*)(Qh + (size_t)(q0 + qt2 * 16 + lr) * DK + kc * 32 + lg * 8);

  bf16x8 kaA[4][2], kaB[4][2];
#pragma unroll
  for (int kt = 0; kt < 4; ++kt)
#pragma unroll
    for (int kc = 0; kc < 2; ++kc)
      kaA[kt][kc] = *(const bf16x8*)(Kh + (size_t)(kt * 16 + lr) * DK + kc * 32 + lg * 8);

  f32x4 o[2][4];
  float m2[2] = {-3e38f, -3e38f}, l2[2] = {0.f, 0.f};
#pragma unroll
  for (int qt2 = 0; qt2 < 2; ++qt2)
#pragma unroll
    for (int dt = 0; dt < 4; ++dt) o[qt2][dt] = (f32x4){0, 0, 0, 0};

  int jd = q0 >> 6;                 // unmasked iters [0,jd), masked iter = jd
  bool useA = true;
  for (int j = 0; j < jd; ++j) {
    if (useA) attn_step<false, true>(Kh, Vh, j * 64, q0, lr, lg, bq, kaA, kaB, o, m2, l2);
    else      attn_step<false, true>(Kh, Vh, j * 64, q0, lr, lg, bq, kaB, kaA, o, m2, l2);
    useA = !useA;
  }
  if (useA) attn_step<true, false>(Kh, Vh, jd * 64, q0, lr, lg, bq, kaA, kaB, o, m2, l2);
  else      attn_step<true, false>(Kh, Vh, jd * 64, q0, lr, lg, bq, kaB, kaA, o, m2, l2);

  // epilogue: AO[b, s, h, dk]; q = lane-local (lr), d = 16dt+4lg+i
  int b = bh >> 4, h = bh & 15;
#pragma unroll
  for (int qt2 = 0; qt2 < 2; ++qt2) {
    float inv = 1.f / l2[qt2];
    int s = q0 + qt2 * 16 + lr;
#pragma unroll
    for (int dt = 0; dt < 4; ++dt) {
      bf16x4 w;
#pragma unroll
      for (int i = 0; i < 4; ++i) w[i] = (__bf16)(o[qt2][dt][i] * inv);
      *(bf16x4*)&AO[(((size_t)(b * S + s)) * H + h) * DK + dt * 16 + lg * 4] = w;
    }
  }
}

extern "C" void kernel_launch(void* const* d_in, const int* in_sizes, int n_in,
                              void* d_out, int out_size, void* d_ws, size_t ws_size,
                              hipStream_t stream) {
  const float* k_in = (const float*)d_in[0];
  const float* q_in = (const float*)d_in[1];
  const float* v_in = (const float*)d_in[2];
  const float* sinp = (const float*)d_in[4];
  const float* cosp = (const float*)d_in[5];
  const float* Wk = (const float*)d_in[6];
  const float* bk = (const float*)d_in[7];
  const float* Wq = (const float*)d_in[8];
  const float* bq = (const float*)d_in[9];
  const float* Wv = (const float*)d_in[10];
  const float* bv = (const float*)d_in[11];
  const float* Wo = (const float*)d_in[12];
  const float* bo = (const float*)d_in[13];
  float* out = (float*)d_out;

  __bf16* ws   = (__bf16*)d_ws;
  __bf16* Xq   = ws;                   // [4096][1024]
  __bf16* Xk   = ws + NE;
  __bf16* Xv   = ws + 2 * NE;
  __bf16* Wall = ws + 3 * NE;          // [Wq|Wk|Wv|Wo]
  __bf16* Qr   = ws + 3 * NE + 4 * WE; // (b,h,s,dk), pre-scaled
  __bf16* Kr   = Qr + NE;
  __bf16* Vt   = Kr + NE;              // (b,h,dk,s)
  __bf16* AO   = Vt + NE;              // (b,s,h,dk)

  dim3 blk(256);
  cvt_all<<<dim3(512, 7), blk, 0, stream>>>(q_in, k_in, v_in, Wq, Wk, Wv, Wo,
                                            Xq, Xk, Xv, Wall);
  proj_kernel<<<dim3(32, 24), blk, 0, stream>>>(Xq, Xk, Xv, Wall, bq, bk, bv,
                                                sinp, cosp, Qr, Kr, Vt);
  attn_kernel<<<2048, dim3(64), 0, stream>>>(Qr, Kr, Vt, AO);
  outproj_kernel<<<dim3(32, 8), blk, 0, stream>>>(AO, Wall + 3 * WE, bo, out);
}

// Round 5
// 213.060 us; speedup vs baseline: 3.3080x; 1.0584x over previous
//
#include <hip/hip_runtime.h>
#include <hip/hip_bf16.h>

typedef __bf16 bf16x8 __attribute__((ext_vector_type(8)));
typedef __bf16 bf16x4 __attribute__((ext_vector_type(4)));
typedef float  f32x4  __attribute__((ext_vector_type(4)));

static constexpr int B = 2, S = 2048, D = 1024, H = 16, DK = 64;
static constexpr int M = B * S;          // 4096
static constexpr int NE = M * D;         // 4194304
static constexpr int WE = D * D;         // 1048576

__device__ inline float fast_exp2(float x) { return __builtin_amdgcn_exp2f(x); }

__device__ inline void gload16(const void* g, void* l) {
  __builtin_amdgcn_global_load_lds(
      (const __attribute__((address_space(1))) void*)g,
      (__attribute__((address_space(3))) void*)l, 16, 0, 0);
}

// zero-shuffle V permutation: store kv-inner i (i=32kc+16a+4lg+r) at lg*16+kc*8+a*4+r
__device__ inline int perm64(int i) {
  return (((i >> 2) & 3) << 4) | (((i >> 5) & 1) << 3) | (((i >> 4) & 1) << 2) | (i & 3);
}

// ---------------- f32 -> bf16 conversion, all tensors in one launch --------
__global__ __launch_bounds__(256) void cvt_all(
    const float* __restrict__ q, const float* __restrict__ k,
    const float* __restrict__ v, const float* __restrict__ Wq,
    const float* __restrict__ Wk, const float* __restrict__ Wv,
    const float* __restrict__ Wo,
    __bf16* __restrict__ Xq, __bf16* __restrict__ Xk,
    __bf16* __restrict__ Xv, __bf16* __restrict__ Wall)
{
  int z = blockIdx.y;
  const float* src; __bf16* dst; int n4;
  switch (z) {
    case 0: src = q;  dst = Xq;            n4 = NE / 4; break;
    case 1: src = k;  dst = Xk;            n4 = NE / 4; break;
    case 2: src = v;  dst = Xv;            n4 = NE / 4; break;
    case 3: src = Wq; dst = Wall;          n4 = WE / 4; break;
    case 4: src = Wk; dst = Wall + WE;     n4 = WE / 4; break;
    case 5: src = Wv; dst = Wall + 2*WE;   n4 = WE / 4; break;
    default:src = Wo; dst = Wall + 3*WE;   n4 = WE / 4; break;
  }
  int i = blockIdx.x * blockDim.x + threadIdx.x;
  int stride = gridDim.x * blockDim.x;
  for (; i < n4; i += stride) {
    float4 f = reinterpret_cast<const float4*>(src)[i];
    bf16x4 o;
    o[0] = (__bf16)f.x; o[1] = (__bf16)f.y; o[2] = (__bf16)f.z; o[3] = (__bf16)f.w;
    reinterpret_cast<bf16x4*>(dst)[i] = o;
  }
}

// ---------------- fused QKV projection, m97-structure 128x128 GEMM ---------
// C[M=4096, Nfused=3072] = X_z @ W_z^T + b_z ; epilogue RoPE (Q,K) / V^T
// Q pre-scaled by 0.125*log2(e); V stored transposed with perm64'd s-inner.
__global__ __launch_bounds__(256) void proj_kernel(
    const __bf16* __restrict__ Xq, const __bf16* __restrict__ Xk,
    const __bf16* __restrict__ Xv, const __bf16* __restrict__ Wall,
    const float* __restrict__ bq_, const float* __restrict__ bk_,
    const float* __restrict__ bv_,
    const float* __restrict__ sinp, const float* __restrict__ cosp,
    __bf16* __restrict__ Qr, __bf16* __restrict__ Kr, __bf16* __restrict__ Vt)
{
  __shared__ __align__(16) __bf16 As[128 * 32];
  __shared__ __align__(16) __bf16 Bs[128 * 32];
  int tid = threadIdx.x;
  int lane = tid & 63, wid = tid >> 6;
  int lr = lane & 15, lg = lane >> 4;
  int wr = wid >> 1, wc = wid & 1;
  int m0 = blockIdx.x * 128;
  int by = blockIdx.y;                  // 0..23 (fused n-tile)
  int z  = by >> 3;                     // 0:Q 1:K 2:V (block-uniform)
  const __bf16* A    = (z == 0) ? Xq : (z == 1) ? Xk : Xv;
  const __bf16* Bw   = Wall + (size_t)by * 128 * 1024;
  const float*  bias = (z == 0) ? bq_ : (z == 1) ? bk_ : bv_;

  int off0 = tid * 16;                  // byte offset in 8KB tile
  int row0 = off0 >> 6;                 // 64 B per LDS row (32 bf16)
  int ce0  = (off0 & 63) >> 1;
  char* asw = (char*)As + wid * 1024;
  char* bsw = (char*)Bs + wid * 1024;

  f32x4 acc[4][4];
#pragma unroll
  for (int i = 0; i < 4; ++i)
#pragma unroll
    for (int j = 0; j < 4; ++j) acc[i][j] = (f32x4){0, 0, 0, 0};

  for (int k0 = 0; k0 < 1024; k0 += 32) {
    gload16(A  + (size_t)(m0 + row0)      * 1024 + k0 + ce0, asw);
    gload16(A  + (size_t)(m0 + row0 + 64) * 1024 + k0 + ce0, asw + 4096);
    gload16(Bw + (size_t)(row0)           * 1024 + k0 + ce0, bsw);
    gload16(Bw + (size_t)(row0 + 64)      * 1024 + k0 + ce0, bsw + 4096);
    __syncthreads();
    bf16x8 af[4], bf[4];
#pragma unroll
    for (int mi = 0; mi < 4; ++mi)
      af[mi] = *reinterpret_cast<const bf16x8*>(&As[(wr*64 + mi*16 + lr)*32 + lg*8]);
#pragma unroll
    for (int ni = 0; ni < 4; ++ni)
      bf[ni] = *reinterpret_cast<const bf16x8*>(&Bs[(wc*64 + ni*16 + lr)*32 + lg*8]);
#pragma unroll
    for (int mi = 0; mi < 4; ++mi)
#pragma unroll
      for (int ni = 0; ni < 4; ++ni)
        acc[mi][ni] = __builtin_amdgcn_mfma_f32_16x16x32_bf16(af[mi], bf[ni], acc[mi][ni], 0, 0, 0);
    __syncthreads();
  }

#pragma unroll
  for (int ni = 0; ni < 4; ++ni) {
    int cf  = by * 128 + wc * 64 + ni * 16 + lr;
    int col = cf & 1023;
    int h = col >> 6, dk = col & 63, tt = dk >> 1;
    float bval = bias[col];
#pragma unroll
    for (int mi = 0; mi < 4; ++mi) {
#pragma unroll
      for (int i = 0; i < 4; ++i) {
        int r = m0 + wr * 64 + mi * 16 + lg * 4 + i;
        int s = r & (S - 1), bb = r >> 11;
        float val = acc[mi][ni][i] + bval;
        if (z < 2) {
          float part = __shfl_xor(val, 1);
          float sn = sinp[s * 32 + tt], cs = cosp[s * 32 + tt];
          float ov = (dk & 1) ? (part * sn + val * cs) : (val * cs - part * sn);
          if (z == 0) ov *= 0.18033688011112042f;   // 0.125 * log2(e)
          __bf16* dst = (z == 0) ? Qr : Kr;
          dst[((size_t)(bb * H + h) * S + s) * DK + dk] = (__bf16)ov;
        } else {
          int sp = (s & ~63) | perm64(s & 63);
          Vt[((size_t)(bb * H + h) * DK + dk) * S + sp] = (__bf16)val;
        }
      }
    }
  }
}

// ---------------- output projection, same GEMM structure, f32 out ----------
__global__ __launch_bounds__(256) void outproj_kernel(
    const __bf16* __restrict__ AO, const __bf16* __restrict__ Wo,
    const float* __restrict__ bo_, float* __restrict__ out)
{
  __shared__ __align__(16) __bf16 As[128 * 32];
  __shared__ __align__(16) __bf16 Bs[128 * 32];
  int tid = threadIdx.x;
  int lane = tid & 63, wid = tid >> 6;
  int lr = lane & 15, lg = lane >> 4;
  int wr = wid >> 1, wc = wid & 1;
  int m0 = blockIdx.x * 128;
  int n0 = blockIdx.y * 128;

  int off0 = tid * 16;
  int row0 = off0 >> 6;
  int ce0  = (off0 & 63) >> 1;
  char* asw = (char*)As + wid * 1024;
  char* bsw = (char*)Bs + wid * 1024;

  f32x4 acc[4][4];
#pragma unroll
  for (int i = 0; i < 4; ++i)
#pragma unroll
    for (int j = 0; j < 4; ++j) acc[i][j] = (f32x4){0, 0, 0, 0};

  for (int k0 = 0; k0 < 1024; k0 += 32) {
    gload16(AO + (size_t)(m0 + row0)      * 1024 + k0 + ce0, asw);
    gload16(AO + (size_t)(m0 + row0 + 64) * 1024 + k0 + ce0, asw + 4096);
    gload16(Wo + (size_t)(n0 + row0)      * 1024 + k0 + ce0, bsw);
    gload16(Wo + (size_t)(n0 + row0 + 64) * 1024 + k0 + ce0, bsw + 4096);
    __syncthreads();
    bf16x8 af[4], bf[4];
#pragma unroll
    for (int mi = 0; mi < 4; ++mi)
      af[mi] = *reinterpret_cast<const bf16x8*>(&As[(wr*64 + mi*16 + lr)*32 + lg*8]);
#pragma unroll
    for (int ni = 0; ni < 4; ++ni)
      bf[ni] = *reinterpret_cast<const bf16x8*>(&Bs[(wc*64 + ni*16 + lr)*32 + lg*8]);
#pragma unroll
    for (int mi = 0; mi < 4; ++mi)
#pragma unroll
      for (int ni = 0; ni < 4; ++ni)
        acc[mi][ni] = __builtin_amdgcn_mfma_f32_16x16x32_bf16(af[mi], bf[ni], acc[mi][ni], 0, 0, 0);
    __syncthreads();
  }

#pragma unroll
  for (int ni = 0; ni < 4; ++ni) {
    int c = n0 + wc * 64 + ni * 16 + lr;
    float bval = bo_[c];
#pragma unroll
    for (int mi = 0; mi < 4; ++mi)
#pragma unroll
      for (int i = 0; i < 4; ++i) {
        int r = m0 + wr * 64 + mi * 16 + lg * 4 + i;
        out[(size_t)r * 1024 + c] = acc[mi][ni][i] + bval;
      }
  }
}

// ---------------- flash attention: QBLK=16/wave, KVBLK=64, all in-reg ------
// Swapped operands: QK^T = mfma(K,Q) -> lane holds score row q=lane&15.
// PV = mfma(Vperm, P) with identical k-permutation on both operands.
template<bool MASKED>
__device__ __forceinline__ void attn_step16(
    const __bf16* __restrict__ Kh, const __bf16* __restrict__ Vh,
    int kv0, int q0, int lr, int lg,
    const bf16x8 (&bq)[2], f32x4 (&o)[4], float& m2, float& l2)
{
  // K loads (needed first, by QK^T)
  bf16x8 ka[4][2];
#pragma unroll
  for (int kt = 0; kt < 4; ++kt)
#pragma unroll
    for (int kc = 0; kc < 2; ++kc)
      ka[kt][kc] = *(const bf16x8*)(Kh + (size_t)(kv0 + kt * 16 + lr) * DK + kc * 32 + lg * 8);
  // V loads (needed at end, by PV) — contiguous 2x16B thanks to perm64 layout
  bf16x8 va[4][2];
#pragma unroll
  for (int dt = 0; dt < 4; ++dt) {
    const __bf16* vb = Vh + (size_t)(dt * 16 + lr) * S + kv0 + lg * 16;
    va[dt][0] = *(const bf16x8*)(vb);
    va[dt][1] = *(const bf16x8*)(vb + 8);
  }

  f32x4 sc[4];
#pragma unroll
  for (int kt = 0; kt < 4; ++kt) sc[kt] = (f32x4){0, 0, 0, 0};
#pragma unroll
  for (int kt = 0; kt < 4; ++kt)
#pragma unroll
    for (int kc = 0; kc < 2; ++kc)
      sc[kt] = __builtin_amdgcn_mfma_f32_16x16x32_bf16(ka[kt][kc], bq[kc], sc[kt], 0, 0, 0);

  if (MASKED) {
#pragma unroll
    for (int kt = 0; kt < 4; ++kt)
#pragma unroll
      for (int i = 0; i < 4; ++i)
        if (kv0 + kt * 16 + lg * 4 + i > q0 + lr)
          sc[kt][i] = -3e38f;
  }

  // row max (16 in-lane values + 2 cross-group shfl)
  float tm = fmaxf(
      fmaxf(fmaxf(fmaxf(sc[0][0], sc[0][1]), fmaxf(sc[0][2], sc[0][3])),
            fmaxf(fmaxf(sc[1][0], sc[1][1]), fmaxf(sc[1][2], sc[1][3]))),
      fmaxf(fmaxf(fmaxf(sc[2][0], sc[2][1]), fmaxf(sc[2][2], sc[2][3])),
            fmaxf(fmaxf(sc[3][0], sc[3][1]), fmaxf(sc[3][2], sc[3][3]))));
  tm = fmaxf(tm, __shfl_xor(tm, 16));
  tm = fmaxf(tm, __shfl_xor(tm, 32));
  // defer-max (T13, THR=8 in log2 space)
  if (__any(tm > m2 + 8.0f)) {
    float mn = fmaxf(m2, tm);
    float f = fast_exp2(m2 - mn);
    m2 = mn;
    l2 *= f;
#pragma unroll
    for (int dt = 0; dt < 4; ++dt) o[dt] *= f;
  }
  float p[16];
#pragma unroll
  for (int kt = 0; kt < 4; ++kt)
#pragma unroll
    for (int i = 0; i < 4; ++i)
      p[kt * 4 + i] = fast_exp2(sc[kt][i] - m2);
  float sum = (((p[0] + p[1]) + (p[2] + p[3])) + ((p[4] + p[5]) + (p[6] + p[7]))) +
              (((p[8] + p[9]) + (p[10] + p[11])) + ((p[12] + p[13]) + (p[14] + p[15])));
  sum += __shfl_xor(sum, 16);
  sum += __shfl_xor(sum, 32);
  l2 += sum;
  // P fragments, zero-shuffle: elem j=4a+r <-> kv = 32kc+16a+4lg+r
  bf16x8 pb[2];
#pragma unroll
  for (int kc = 0; kc < 2; ++kc) {
    bf16x8 pv;
#pragma unroll
    for (int a = 0; a < 2; ++a)
#pragma unroll
      for (int r = 0; r < 4; ++r)
        pv[a * 4 + r] = (__bf16)p[(2 * kc + a) * 4 + r];
    pb[kc] = pv;
  }

#pragma unroll
  for (int dt = 0; dt < 4; ++dt)
#pragma unroll
    for (int kc = 0; kc < 2; ++kc)
      o[dt] = __builtin_amdgcn_mfma_f32_16x16x32_bf16(va[dt][kc], pb[kc], o[dt], 0, 0, 0);
}

__global__ __launch_bounds__(64, 4) void attn_kernel(
    const __bf16* __restrict__ Qr, const __bf16* __restrict__ Kr,
    const __bf16* __restrict__ Vt, __bf16* __restrict__ AO)
{
  int lane = threadIdx.x;
  int lr = lane & 15, lg = lane >> 4;
  int bx = blockIdx.x;
  // heavy-first, XCD-clustered: bh fixed per XCD slot, qt descending
  int bh = (bx & 7) * 4 + ((bx >> 3) & 3);
  int qt = 127 - (bx >> 5);
  int q0 = qt * 16;
  const __bf16* Qh = Qr + (size_t)bh * (S * DK);
  const __bf16* Kh = Kr + (size_t)bh * (S * DK);
  const __bf16* Vh = Vt + (size_t)bh * (DK * S);

  bf16x8 bq[2];
#pragma unroll
  for (int kc = 0; kc < 2; ++kc)
    bq[kc] = *(const bf16x8*)(Qh + (size_t)(q0 + lr) * DK + kc * 32 + lg * 8);

  f32x4 o[4];
  float m2 = -3e38f, l2 = 0.f;
#pragma unroll
  for (int dt = 0; dt < 4; ++dt) o[dt] = (f32x4){0, 0, 0, 0};

  int jd = q0 >> 6;                 // unmasked iters [0,jd), masked iter = jd
  for (int j = 0; j < jd; ++j)
    attn_step16<false>(Kh, Vh, j * 64, q0, lr, lg, bq, o, m2, l2);
  attn_step16<true>(Kh, Vh, jd * 64, q0, lr, lg, bq, o, m2, l2);

  // epilogue: AO[b, s, h, dk]; q row = lr, d = 16dt + 4lg + i
  int b = bh >> 4, h = bh & 15;
  float inv = 1.f / l2;
  int s = q0 + lr;
#pragma unroll
  for (int dt = 0; dt < 4; ++dt) {
    bf16x4 w;
#pragma unroll
    for (int i = 0; i < 4; ++i) w[i] = (__bf16)(o[dt][i] * inv);
    *(bf16x4*)&AO[(((size_t)(b * S + s)) * H + h) * DK + dt * 16 + lg * 4] = w;
  }
}

extern "C" void kernel_launch(void* const* d_in, const int* in_sizes, int n_in,
                              void* d_out, int out_size, void* d_ws, size_t ws_size,
                              hipStream_t stream) {
  const float* k_in = (const float*)d_in[0];
  const float* q_in = (const float*)d_in[1];
  const float* v_in = (const float*)d_in[2];
  const float* sinp = (const float*)d_in[4];
  const float* cosp = (const float*)d_in[5];
  const float* Wk = (const float*)d_in[6];
  const float* bk = (const float*)d_in[7];
  const float* Wq = (const float*)d_in[8];
  const float* bq = (const float*)d_in[9];
  const float* Wv = (const float*)d_in[10];
  const float* bv = (const float*)d_in[11];
  const float* Wo = (const float*)d_in[12];
  const float* bo = (const float*)d_in[13];
  float* out = (float*)d_out;

  __bf16* ws   = (__bf16*)d_ws;
  __bf16* Xq   = ws;                   // [4096][1024]
  __bf16* Xk   = ws + NE;
  __bf16* Xv   = ws + 2 * NE;
  __bf16* Wall = ws + 3 * NE;          // [Wq|Wk|Wv|Wo]
  __bf16* Qr   = ws + 3 * NE + 4 * WE; // (b,h,s,dk), pre-scaled
  __bf16* Kr   = Qr + NE;
  __bf16* Vt   = Kr + NE;              // (b,h,dk,s) perm64'd inner
  __bf16* AO   = Vt + NE;              // (b,s,h,dk)

  dim3 blk(256);
  cvt_all<<<dim3(512, 7), blk, 0, stream>>>(q_in, k_in, v_in, Wq, Wk, Wv, Wo,
                                            Xq, Xk, Xv, Wall);
  proj_kernel<<<dim3(32, 24), blk, 0, stream>>>(Xq, Xk, Xv, Wall, bq, bk, bv,
                                                sinp, cosp, Qr, Kr, Vt);
  attn_kernel<<<4096, dim3(64), 0, stream>>>(Qr, Kr, Vt, AO);
  outproj_kernel<<<dim3(32, 8), blk, 0, stream>>>(AO, Wall + 3 * WE, bo, out);
}

// Round 6
// 126.461 us; speedup vs baseline: 5.5732x; 1.6848x over previous
//
#include <hip/hip_runtime.h>
#include <hip/hip_bf16.h>

typedef __bf16 bf16x8 __attribute__((ext_vector_type(8)));
typedef __bf16 bf16x4 __attribute__((ext_vector_type(4)));
typedef float  f32x4  __attribute__((ext_vector_type(4)));

static constexpr int B = 2, S = 2048, D = 1024, H = 16, DK = 64;
static constexpr int M = B * S;          // 4096
static constexpr int NE = M * D;         // 4194304
static constexpr int WE = D * D;         // 1048576

__device__ inline float fast_exp2(float x) { return __builtin_amdgcn_exp2f(x); }

__device__ inline void gload16(const void* g, void* l) {
  __builtin_amdgcn_global_load_lds(
      (const __attribute__((address_space(1))) void*)g,
      (__attribute__((address_space(3))) void*)l, 16, 0, 0);
}

// zero-shuffle V permutation: store kv-inner i (i=32kc+16a+4lg+r) at lg*16+kc*8+a*4+r
__device__ inline int perm64(int i) {
  return (((i >> 2) & 3) << 4) | (((i >> 5) & 1) << 3) | (((i >> 4) & 1) << 2) | (i & 3);
}

// ---------------- f32 -> bf16 conversion, all tensors in one launch --------
__global__ __launch_bounds__(256) void cvt_all(
    const float* __restrict__ q, const float* __restrict__ k,
    const float* __restrict__ v, const float* __restrict__ Wq,
    const float* __restrict__ Wk, const float* __restrict__ Wv,
    const float* __restrict__ Wo,
    __bf16* __restrict__ Xq, __bf16* __restrict__ Xk,
    __bf16* __restrict__ Xv, __bf16* __restrict__ Wall)
{
  int z = blockIdx.y;
  const float* src; __bf16* dst; int n4;
  switch (z) {
    case 0: src = q;  dst = Xq;            n4 = NE / 4; break;
    case 1: src = k;  dst = Xk;            n4 = NE / 4; break;
    case 2: src = v;  dst = Xv;            n4 = NE / 4; break;
    case 3: src = Wq; dst = Wall;          n4 = WE / 4; break;
    case 4: src = Wk; dst = Wall + WE;     n4 = WE / 4; break;
    case 5: src = Wv; dst = Wall + 2*WE;   n4 = WE / 4; break;
    default:src = Wo; dst = Wall + 3*WE;   n4 = WE / 4; break;
  }
  int i = blockIdx.x * blockDim.x + threadIdx.x;
  int stride = gridDim.x * blockDim.x;
  for (; i < n4; i += stride) {
    float4 f = reinterpret_cast<const float4*>(src)[i];
    bf16x4 o;
    o[0] = (__bf16)f.x; o[1] = (__bf16)f.y; o[2] = (__bf16)f.z; o[3] = (__bf16)f.w;
    reinterpret_cast<bf16x4*>(dst)[i] = o;
  }
}

// ---------------- fused QKV projection, m97-structure 128x128 GEMM ---------
// C[M=4096, Nfused=3072] = X_z @ W_z^T + b_z ; epilogue RoPE (Q,K) / V^T
// Q pre-scaled by 0.125*log2(e); V stored transposed with perm64'd s-inner.
__global__ __launch_bounds__(256) void proj_kernel(
    const __bf16* __restrict__ Xq, const __bf16* __restrict__ Xk,
    const __bf16* __restrict__ Xv, const __bf16* __restrict__ Wall,
    const float* __restrict__ bq_, const float* __restrict__ bk_,
    const float* __restrict__ bv_,
    const float* __restrict__ sinp, const float* __restrict__ cosp,
    __bf16* __restrict__ Qr, __bf16* __restrict__ Kr, __bf16* __restrict__ Vt)
{
  __shared__ __align__(16) __bf16 As[128 * 32];
  __shared__ __align__(16) __bf16 Bs[128 * 32];
  int tid = threadIdx.x;
  int lane = tid & 63, wid = tid >> 6;
  int lr = lane & 15, lg = lane >> 4;
  int wr = wid >> 1, wc = wid & 1;
  int m0 = blockIdx.x * 128;
  int by = blockIdx.y;                  // 0..23 (fused n-tile)
  int z  = by >> 3;                     // 0:Q 1:K 2:V (block-uniform)
  const __bf16* A    = (z == 0) ? Xq : (z == 1) ? Xk : Xv;
  const __bf16* Bw   = Wall + (size_t)by * 128 * 1024;
  const float*  bias = (z == 0) ? bq_ : (z == 1) ? bk_ : bv_;

  int off0 = tid * 16;                  // byte offset in 8KB tile
  int row0 = off0 >> 6;                 // 64 B per LDS row (32 bf16)
  int ce0  = (off0 & 63) >> 1;
  char* asw = (char*)As + wid * 1024;
  char* bsw = (char*)Bs + wid * 1024;

  f32x4 acc[4][4];
#pragma unroll
  for (int i = 0; i < 4; ++i)
#pragma unroll
    for (int j = 0; j < 4; ++j) acc[i][j] = (f32x4){0, 0, 0, 0};

  for (int k0 = 0; k0 < 1024; k0 += 32) {
    gload16(A  + (size_t)(m0 + row0)      * 1024 + k0 + ce0, asw);
    gload16(A  + (size_t)(m0 + row0 + 64) * 1024 + k0 + ce0, asw + 4096);
    gload16(Bw + (size_t)(row0)           * 1024 + k0 + ce0, bsw);
    gload16(Bw + (size_t)(row0 + 64)      * 1024 + k0 + ce0, bsw + 4096);
    __syncthreads();
    bf16x8 af[4], bf[4];
#pragma unroll
    for (int mi = 0; mi < 4; ++mi)
      af[mi] = *reinterpret_cast<const bf16x8*>(&As[(wr*64 + mi*16 + lr)*32 + lg*8]);
#pragma unroll
    for (int ni = 0; ni < 4; ++ni)
      bf[ni] = *reinterpret_cast<const bf16x8*>(&Bs[(wc*64 + ni*16 + lr)*32 + lg*8]);
#pragma unroll
    for (int mi = 0; mi < 4; ++mi)
#pragma unroll
      for (int ni = 0; ni < 4; ++ni)
        acc[mi][ni] = __builtin_amdgcn_mfma_f32_16x16x32_bf16(af[mi], bf[ni], acc[mi][ni], 0, 0, 0);
    __syncthreads();
  }

#pragma unroll
  for (int ni = 0; ni < 4; ++ni) {
    int cf  = by * 128 + wc * 64 + ni * 16 + lr;
    int col = cf & 1023;
    int h = col >> 6, dk = col & 63, tt = dk >> 1;
    float bval = bias[col];
#pragma unroll
    for (int mi = 0; mi < 4; ++mi) {
#pragma unroll
      for (int i = 0; i < 4; ++i) {
        int r = m0 + wr * 64 + mi * 16 + lg * 4 + i;
        int s = r & (S - 1), bb = r >> 11;
        float val = acc[mi][ni][i] + bval;
        if (z < 2) {
          float part = __shfl_xor(val, 1);
          float sn = sinp[s * 32 + tt], cs = cosp[s * 32 + tt];
          float ov = (dk & 1) ? (part * sn + val * cs) : (val * cs - part * sn);
          if (z == 0) ov *= 0.18033688011112042f;   // 0.125 * log2(e)
          __bf16* dst = (z == 0) ? Qr : Kr;
          dst[((size_t)(bb * H + h) * S + s) * DK + dk] = (__bf16)ov;
        } else {
          int sp = (s & ~63) | perm64(s & 63);
          Vt[((size_t)(bb * H + h) * DK + dk) * S + sp] = (__bf16)val;
        }
      }
    }
  }
}

// ---------------- output projection, same GEMM structure, f32 out ----------
__global__ __launch_bounds__(256) void outproj_kernel(
    const __bf16* __restrict__ AO, const __bf16* __restrict__ Wo,
    const float* __restrict__ bo_, float* __restrict__ out)
{
  __shared__ __align__(16) __bf16 As[128 * 32];
  __shared__ __align__(16) __bf16 Bs[128 * 32];
  int tid = threadIdx.x;
  int lane = tid & 63, wid = tid >> 6;
  int lr = lane & 15, lg = lane >> 4;
  int wr = wid >> 1, wc = wid & 1;
  int m0 = blockIdx.x * 128;
  int n0 = blockIdx.y * 128;

  int off0 = tid * 16;
  int row0 = off0 >> 6;
  int ce0  = (off0 & 63) >> 1;
  char* asw = (char*)As + wid * 1024;
  char* bsw = (char*)Bs + wid * 1024;

  f32x4 acc[4][4];
#pragma unroll
  for (int i = 0; i < 4; ++i)
#pragma unroll
    for (int j = 0; j < 4; ++j) acc[i][j] = (f32x4){0, 0, 0, 0};

  for (int k0 = 0; k0 < 1024; k0 += 32) {
    gload16(AO + (size_t)(m0 + row0)      * 1024 + k0 + ce0, asw);
    gload16(AO + (size_t)(m0 + row0 + 64) * 1024 + k0 + ce0, asw + 4096);
    gload16(Wo + (size_t)(n0 + row0)      * 1024 + k0 + ce0, bsw);
    gload16(Wo + (size_t)(n0 + row0 + 64) * 1024 + k0 + ce0, bsw + 4096);
    __syncthreads();
    bf16x8 af[4], bf[4];
#pragma unroll
    for (int mi = 0; mi < 4; ++mi)
      af[mi] = *reinterpret_cast<const bf16x8*>(&As[(wr*64 + mi*16 + lr)*32 + lg*8]);
#pragma unroll
    for (int ni = 0; ni < 4; ++ni)
      bf[ni] = *reinterpret_cast<const bf16x8*>(&Bs[(wc*64 + ni*16 + lr)*32 + lg*8]);
#pragma unroll
    for (int mi = 0; mi < 4; ++mi)
#pragma unroll
      for (int ni = 0; ni < 4; ++ni)
        acc[mi][ni] = __builtin_amdgcn_mfma_f32_16x16x32_bf16(af[mi], bf[ni], acc[mi][ni], 0, 0, 0);
    __syncthreads();
  }

#pragma unroll
  for (int ni = 0; ni < 4; ++ni) {
    int c = n0 + wc * 64 + ni * 16 + lr;
    float bval = bo_[c];
#pragma unroll
    for (int mi = 0; mi < 4; ++mi)
#pragma unroll
      for (int i = 0; i < 4; ++i) {
        int r = m0 + wr * 64 + mi * 16 + lg * 4 + i;
        out[(size_t)r * 1024 + c] = acc[mi][ni][i] + bval;
      }
  }
}

// ---------------- flash attention: 4-warp block, LDS-shared K/V ------------
// Block = 64 q-rows (16/warp), KVBLK=64, K+V double-buffered in LDS with
// global_load_lds prefetch (T3-minimum 2-phase). LDS layout XOR-swizzled
// (byte ^= (row&7)<<4) via pre-swizzled global source (rule #21).
// Swapped operands: QK^T = mfma(K,Q) -> lane holds score row q=lane&15;
// PV = mfma(Vperm,P), identical k-permutation both operands (zero-shuffle).
__global__ __launch_bounds__(256, 4) void attn_kernel(
    const __bf16* __restrict__ Qr, const __bf16* __restrict__ Kr,
    const __bf16* __restrict__ Vt, __bf16* __restrict__ AO)
{
  __shared__ __align__(16) char smem[32768];   // [2][ K 8KB | V 8KB ]
  int tid = threadIdx.x;
  int lane = tid & 63, wid = tid >> 6;
  int lr = lane & 15, lg = lane >> 4;
  int bx = blockIdx.x;
  int bh = (bx & 7) * 4 + ((bx >> 3) & 3);   // XCD-spread (b*H+h)
  int qb = 31 - (bx >> 5);                   // heavy blocks dispatched first
  int q0 = qb * 64 + wid * 16;               // this warp's 16 q-rows
  int nsteps = qb + 1;

  const char* Kb = (const char*)(Kr + (size_t)bh * S * DK);  // row stride 128B
  const char* Vb = (const char*)(Vt + (size_t)bh * DK * S);  // row stride 4096B
  const __bf16* Qh = Qr + (size_t)bh * S * DK;

  // staging: 256 threads x 16B x 2 instrs per 8KB tile; source pre-swizzled
  int o_lo = wid * 1024 + lane * 16;
#define STAGE(sel, kv0)                                                        \
  {                                                                            \
    char* kdst = smem + (sel) * 16384;                                         \
    _Pragma("unroll")                                                          \
    for (int i = 0; i < 2; ++i) {                                              \
      int o = o_lo + i * 4096;                                                 \
      int row = o >> 7;                                                        \
      int colp = (o & 127) ^ ((row & 7) << 4);                                 \
      gload16(Kb + (((size_t)((kv0) + row)) << 7) + colp,                      \
              kdst + wid * 1024 + i * 4096);                                   \
      gload16(Vb + ((size_t)row * S + (kv0)) * 2 + colp,                       \
              kdst + 8192 + wid * 1024 + i * 4096);                            \
    }                                                                          \
  }

  // Q fragments (8 dk elems each, k-dim = dk)
  bf16x8 bq[2];
#pragma unroll
  for (int kc = 0; kc < 2; ++kc)
    bq[kc] = *(const bf16x8*)(Qh + (size_t)(q0 + lr) * DK + kc * 32 + lg * 8);

  // per-lane swizzled LDS byte offsets (constant across steps)
  int swz = (lr & 7) << 4;
  int oK0 = lr * 128 + ((lg * 16) ^ swz);
  int oK1 = lr * 128 + ((64 + lg * 16) ^ swz);
  int oV0 = lr * 128 + ((lg * 32) ^ swz);
  int oV1 = lr * 128 + ((16 + lg * 32) ^ swz);

  f32x4 o[4];
  float m2 = -3e38f, l2 = 0.f;
#pragma unroll
  for (int dt = 0; dt < 4; ++dt) o[dt] = (f32x4){0, 0, 0, 0};

  STAGE(0, 0);
  __syncthreads();

  for (int j = 0; j < nsteps; ++j) {
    int sel = j & 1;
    if (j + 1 < nsteps) STAGE(sel ^ 1, (j + 1) * 64);
    const char* kbuf = smem + sel * 16384;
    const char* vbuf = kbuf + 8192;
    int kv0 = j * 64;

    // QK^T: sc[kt][i] = score(kv = kv0+kt*16+4lg+i, q = q0+lr)
    f32x4 sc[4];
#pragma unroll
    for (int kt = 0; kt < 4; ++kt) {
      bf16x8 ka0 = *(const bf16x8*)(kbuf + oK0 + kt * 2048);
      bf16x8 ka1 = *(const bf16x8*)(kbuf + oK1 + kt * 2048);
      f32x4 s = (f32x4){0, 0, 0, 0};
      s = __builtin_amdgcn_mfma_f32_16x16x32_bf16(ka0, bq[0], s, 0, 0, 0);
      s = __builtin_amdgcn_mfma_f32_16x16x32_bf16(ka1, bq[1], s, 0, 0, 0);
      sc[kt] = s;
    }

    if (j == qb) {   // diagonal step: causal mask
#pragma unroll
      for (int kt = 0; kt < 4; ++kt)
#pragma unroll
        for (int i = 0; i < 4; ++i)
          if (kv0 + kt * 16 + lg * 4 + i > q0 + lr)
            sc[kt][i] = -3e38f;
    }

    // row max (16 in-lane + 2 cross-group shfl)
    float tm = fmaxf(
        fmaxf(fmaxf(fmaxf(sc[0][0], sc[0][1]), fmaxf(sc[0][2], sc[0][3])),
              fmaxf(fmaxf(sc[1][0], sc[1][1]), fmaxf(sc[1][2], sc[1][3]))),
        fmaxf(fmaxf(fmaxf(sc[2][0], sc[2][1]), fmaxf(sc[2][2], sc[2][3])),
              fmaxf(fmaxf(sc[3][0], sc[3][1]), fmaxf(sc[3][2], sc[3][3]))));
    tm = fmaxf(tm, __shfl_xor(tm, 16));
    tm = fmaxf(tm, __shfl_xor(tm, 32));
    // defer-max (T13, THR=8 in log2 space)
    if (__any(tm > m2 + 8.0f)) {
      float mn = fmaxf(m2, tm);
      float f = fast_exp2(m2 - mn);
      m2 = mn;
      l2 *= f;
#pragma unroll
      for (int dt = 0; dt < 4; ++dt) o[dt] *= f;
    }
    float p[16];
#pragma unroll
    for (int kt = 0; kt < 4; ++kt)
#pragma unroll
      for (int i = 0; i < 4; ++i)
        p[kt * 4 + i] = fast_exp2(sc[kt][i] - m2);
    float sum = (((p[0] + p[1]) + (p[2] + p[3])) + ((p[4] + p[5]) + (p[6] + p[7]))) +
                (((p[8] + p[9]) + (p[10] + p[11])) + ((p[12] + p[13]) + (p[14] + p[15])));
    sum += __shfl_xor(sum, 16);
    sum += __shfl_xor(sum, 32);
    l2 += sum;
    // P fragments, zero-shuffle: elem j=4a+r <-> kv = 32kc+16a+4lg+r
    bf16x8 pb[2];
#pragma unroll
    for (int kc = 0; kc < 2; ++kc) {
      bf16x8 pv;
#pragma unroll
      for (int a = 0; a < 2; ++a)
#pragma unroll
        for (int r = 0; r < 4; ++r)
          pv[a * 4 + r] = (__bf16)p[(2 * kc + a) * 4 + r];
      pb[kc] = pv;
    }

    // PV: o[dt] lane holds q=lane&15 (col), d = 16*dt + 4*lg + reg (row)
#pragma unroll
    for (int dt = 0; dt < 4; ++dt) {
      bf16x8 v0 = *(const bf16x8*)(vbuf + oV0 + dt * 2048);
      bf16x8 v1 = *(const bf16x8*)(vbuf + oV1 + dt * 2048);
      o[dt] = __builtin_amdgcn_mfma_f32_16x16x32_bf16(v0, pb[0], o[dt], 0, 0, 0);
      o[dt] = __builtin_amdgcn_mfma_f32_16x16x32_bf16(v1, pb[1], o[dt], 0, 0, 0);
    }
    __syncthreads();
  }
#undef STAGE

  // epilogue: AO[b, s, h, dk]; q row = lr, d = 16dt + 4lg + i
  int b = bh >> 4, h = bh & 15;
  float inv = 1.f / l2;
  int s = q0 + lr;
#pragma unroll
  for (int dt = 0; dt < 4; ++dt) {
    bf16x4 w;
#pragma unroll
    for (int i = 0; i < 4; ++i) w[i] = (__bf16)(o[dt][i] * inv);
    *(bf16x4*)&AO[(((size_t)(b * S + s)) * H + h) * DK + dt * 16 + lg * 4] = w;
  }
}

extern "C" void kernel_launch(void* const* d_in, const int* in_sizes, int n_in,
                              void* d_out, int out_size, void* d_ws, size_t ws_size,
                              hipStream_t stream) {
  const float* k_in = (const float*)d_in[0];
  const float* q_in = (const float*)d_in[1];
  const float* v_in = (const float*)d_in[2];
  const float* sinp = (const float*)d_in[4];
  const float* cosp = (const float*)d_in[5];
  const float* Wk = (const float*)d_in[6];
  const float* bk = (const float*)d_in[7];
  const float* Wq = (const float*)d_in[8];
  const float* bq = (const float*)d_in[9];
  const float* Wv = (const float*)d_in[10];
  const float* bv = (const float*)d_in[11];
  const float* Wo = (const float*)d_in[12];
  const float* bo = (const float*)d_in[13];
  float* out = (float*)d_out;

  __bf16* ws   = (__bf16*)d_ws;
  __bf16* Xq   = ws;                   // [4096][1024]
  __bf16* Xk   = ws + NE;
  __bf16* Xv   = ws + 2 * NE;
  __bf16* Wall = ws + 3 * NE;          // [Wq|Wk|Wv|Wo]
  __bf16* Qr   = ws + 3 * NE + 4 * WE; // (b,h,s,dk), pre-scaled
  __bf16* Kr   = Qr + NE;
  __bf16* Vt   = Kr + NE;              // (b,h,dk,s) perm64'd inner
  __bf16* AO   = Vt + NE;              // (b,s,h,dk)

  dim3 blk(256);
  cvt_all<<<dim3(512, 7), blk, 0, stream>>>(q_in, k_in, v_in, Wq, Wk, Wv, Wo,
                                            Xq, Xk, Xv, Wall);
  proj_kernel<<<dim3(32, 24), blk, 0, stream>>>(Xq, Xk, Xv, Wall, bq, bk, bv,
                                                sinp, cosp, Qr, Kr, Vt);
  attn_kernel<<<1024, blk, 0, stream>>>(Qr, Kr, Vt, AO);
  outproj_kernel<<<dim3(32, 8), blk, 0, stream>>>(AO, Wall + 3 * WE, bo, out);
}